// Round 1
// baseline (846.909 us; speedup 1.0000x reference)
//
#include <hip/hip_runtime.h>
#include <cstddef>

constexpr int NN    = 8192;
constexpr int DIN   = 1024;
constexpr int DMID  = 256;
constexpr int DEMB  = 64;
constexpr int NEDGE = 65536;

// ---------------- generic fp32 tiled GEMM (all dims divide tile sizes) ----------------
template<int BM, int BN, int BK, int TM, int TN, bool RELUA>
__global__ __launch_bounds__(256) void sgemm_kernel(
    const float* __restrict__ A, const float* __restrict__ B,
    float* __restrict__ C, int M, int N, int K)
{
  constexpr int TX = BN / TN;
  constexpr int TY = BM / TM;
  static_assert(TX * TY == 256, "block must be 256 threads");
  __shared__ float As[BK][BM + 4];   // transposed: As[k][m]
  __shared__ float Bs[BK][BN + 4];   // Bs[k][n]

  const int tid = threadIdx.x;
  const int tx  = tid % TX;
  const int ty  = tid / TX;
  const int m0  = blockIdx.y * BM;
  const int n0  = blockIdx.x * BN;

  float acc[TM][TN];
#pragma unroll
  for (int i = 0; i < TM; ++i)
#pragma unroll
    for (int j = 0; j < TN; ++j) acc[i][j] = 0.f;

  constexpr int A_PER = (BM * BK / 4) / 256;
  constexpr int B_PER = (BK * BN / 4) / 256;
  static_assert((BM * BK / 4) % 256 == 0 && (BK * BN / 4) % 256 == 0, "tile load");

  for (int k0 = 0; k0 < K; k0 += BK) {
#pragma unroll
    for (int f = 0; f < A_PER; ++f) {
      int idx = tid + f * 256;            // float4 index in A tile
      int row = idx / (BK / 4);
      int kc  = (idx % (BK / 4)) * 4;
      float4 v = *(const float4*)(A + (size_t)(m0 + row) * K + k0 + kc);
      if (RELUA) {
        v.x = fmaxf(v.x, 0.f); v.y = fmaxf(v.y, 0.f);
        v.z = fmaxf(v.z, 0.f); v.w = fmaxf(v.w, 0.f);
      }
      As[kc + 0][row] = v.x; As[kc + 1][row] = v.y;
      As[kc + 2][row] = v.z; As[kc + 3][row] = v.w;
    }
#pragma unroll
    for (int f = 0; f < B_PER; ++f) {
      int idx = tid + f * 256;
      int kr  = idx / (BN / 4);
      int nc  = (idx % (BN / 4)) * 4;
      *(float4*)&Bs[kr][nc] = *(const float4*)(B + (size_t)(k0 + kr) * N + n0 + nc);
    }
    __syncthreads();
#pragma unroll
    for (int k = 0; k < BK; ++k) {
      float a[TM], b[TN];
#pragma unroll
      for (int i = 0; i < TM; i += 4)
        *(float4*)&a[i] = *(const float4*)&As[k][ty * TM + i];
#pragma unroll
      for (int j = 0; j < TN; j += 4)
        *(float4*)&b[j] = *(const float4*)&Bs[k][tx * TN + j];
#pragma unroll
      for (int i = 0; i < TM; ++i)
#pragma unroll
        for (int j = 0; j < TN; ++j)
          acc[i][j] = fmaf(a[i], b[j], acc[i][j]);
    }
    __syncthreads();
  }
#pragma unroll
  for (int i = 0; i < TM; ++i)
#pragma unroll
    for (int j = 0; j < TN; j += 4) {
      float4 v;
      v.x = acc[i][j]; v.y = acc[i][j + 1]; v.z = acc[i][j + 2]; v.w = acc[i][j + 3];
      *(float4*)(C + (size_t)(m0 + ty * TM + i) * N + n0 + tx * TN + j) = v;
    }
}

// ---------------- COO spmm: out[dst] += ev * H[src], atomic scatter-add ----------------
template<int D>
__global__ __launch_bounds__(256) void spmm_kernel(
    const float* __restrict__ H, const float* __restrict__ ev,
    const int* __restrict__ src, const int* __restrict__ dst,
    float* __restrict__ out)
{
  constexpr int TPE = D / 4;      // threads per edge (float4 per thread)
  const int t = threadIdx.x;
  const int e = blockIdx.x * (256 / TPE) + t / TPE;
  const int c = (t % TPE) * 4;
  const float v = ev[e];
  const int s = src[e];
  const int d = dst[e];
  float4 h = *(const float4*)(H + (size_t)s * D + c);
  float* o = out + (size_t)d * D + c;
  atomicAdd(o + 0, v * h.x);
  atomicAdd(o + 1, v * h.y);
  atomicAdd(o + 2, v * h.z);
  atomicAdd(o + 3, v * h.w);
}

// ---------------- row squared-norms of Emb ----------------
__global__ __launch_bounds__(256) void sq_kernel(const float* __restrict__ E, float* __restrict__ sq)
{
  int r = blockIdx.x * 256 + threadIdx.x;
  const float4* p = (const float4*)(E + (size_t)r * DEMB);
  float s = 0.f;
#pragma unroll
  for (int i = 0; i < DEMB / 4; ++i) {
    float4 v = p[i];
    s += v.x * v.x + v.y * v.y + v.z * v.z + v.w * v.w;
  }
  sq[r] = s;
}

// ---------------- dist = sq_i + sq_j - 2*Emb@Emb.T ; write exp(-dist), accumulate rowsums ----
__global__ __launch_bounds__(256) void dist_exp_kernel(
    const float* __restrict__ E, const float* __restrict__ sq,
    float* __restrict__ out, float* __restrict__ rowsum)
{
  __shared__ float As[16][132];
  __shared__ float Bs[16][132];
  __shared__ float red[128][17];
  const int tid = threadIdx.x;
  const int tx  = tid % 16;
  const int ty  = tid / 16;
  const int i0  = blockIdx.y * 128;
  const int j0  = blockIdx.x * 128;

  float acc[8][8];
#pragma unroll
  for (int i = 0; i < 8; ++i)
#pragma unroll
    for (int j = 0; j < 8; ++j) acc[i][j] = 0.f;

  for (int k0 = 0; k0 < DEMB; k0 += 16) {
#pragma unroll
    for (int f = 0; f < 2; ++f) {
      int idx = tid + f * 256;
      int row = idx / 4;
      int kc  = (idx % 4) * 4;
      float4 a = *(const float4*)(E + (size_t)(i0 + row) * DEMB + k0 + kc);
      As[kc + 0][row] = a.x; As[kc + 1][row] = a.y; As[kc + 2][row] = a.z; As[kc + 3][row] = a.w;
      float4 b = *(const float4*)(E + (size_t)(j0 + row) * DEMB + k0 + kc);
      Bs[kc + 0][row] = b.x; Bs[kc + 1][row] = b.y; Bs[kc + 2][row] = b.z; Bs[kc + 3][row] = b.w;
    }
    __syncthreads();
#pragma unroll
    for (int k = 0; k < 16; ++k) {
      float a[8], b[8];
      *(float4*)&a[0] = *(const float4*)&As[k][ty * 8];
      *(float4*)&a[4] = *(const float4*)&As[k][ty * 8 + 4];
      *(float4*)&b[0] = *(const float4*)&Bs[k][tx * 8];
      *(float4*)&b[4] = *(const float4*)&Bs[k][tx * 8 + 4];
#pragma unroll
      for (int i = 0; i < 8; ++i)
#pragma unroll
        for (int j = 0; j < 8; ++j)
          acc[i][j] = fmaf(a[i], b[j], acc[i][j]);
    }
    __syncthreads();
  }

  float si[8], sj[8];
#pragma unroll
  for (int i = 0; i < 8; ++i) si[i] = sq[i0 + ty * 8 + i];
#pragma unroll
  for (int j = 0; j < 8; ++j) sj[j] = sq[j0 + tx * 8 + j];

#pragma unroll
  for (int i = 0; i < 8; ++i) {
    float evv[8];
    float rp = 0.f;
#pragma unroll
    for (int j = 0; j < 8; ++j) {
      // -dist = 2*dot - sq_i - sq_j ; dist_ii == 0 so no overflow, max-subtract unneeded
      evv[j] = __expf(fmaf(2.f, acc[i][j], -si[i] - sj[j]));
      rp += evv[j];
    }
    float4 e0, e1;
    e0.x = evv[0]; e0.y = evv[1]; e0.z = evv[2]; e0.w = evv[3];
    e1.x = evv[4]; e1.y = evv[5]; e1.z = evv[6]; e1.w = evv[7];
    size_t base = (size_t)(i0 + ty * 8 + i) * NN + j0 + tx * 8;
    *(float4*)(out + base)     = e0;
    *(float4*)(out + base + 4) = e1;
    red[ty * 8 + i][tx] = rp;
  }
  __syncthreads();
  if (tid < 128) {
    float s = 0.f;
#pragma unroll
    for (int t = 0; t < 16; ++t) s += red[tid][t];
    atomicAdd(rowsum + i0 + tid, s);
  }
}

__global__ __launch_bounds__(256) void inv_kernel(const float* __restrict__ rowsum,
                                                  float* __restrict__ inv)
{
  int i = blockIdx.x * 256 + threadIdx.x;
  inv[i] = 1.f / rowsum[i];
}

__global__ __launch_bounds__(256) void scale_kernel(float* __restrict__ out,
                                                    const float* __restrict__ inv)
{
  size_t idx = (size_t)blockIdx.x * 256 + threadIdx.x;  // float4 index
  int row = (int)(idx >> 11);                           // 2048 float4 per row
  float s = inv[row];
  float4* p = (float4*)out + idx;
  float4 v = *p;
  v.x = fmaf(v.x, s, 1e-10f);
  v.y = fmaf(v.y, s, 1e-10f);
  v.z = fmaf(v.z, s, 1e-10f);
  v.w = fmaf(v.w, s, 1e-10f);
  *p = v;
}

extern "C" void kernel_launch(void* const* d_in, const int* in_sizes, int n_in,
                              void* d_out, int out_size, void* d_ws, size_t ws_size,
                              hipStream_t stream)
{
  const float* X  = (const float*)d_in[0];
  const float* W1 = (const float*)d_in[1];
  const float* W2 = (const float*)d_in[2];
  const float* ev = (const float*)d_in[3];
  const int* esrc = (const int*)d_in[4];
  const int* edst = (const int*)d_in[5];
  float* out = (float*)d_out;

  // workspace layout: [zero-init block: H1s | Emb | rowsum] [H1 | E1 | sq | inv]
  float* H1s    = (float*)d_ws;                 // [NN][DMID]  (zeroed)
  float* Emb    = H1s + (size_t)NN * DMID;      // [NN][DEMB]  (zeroed)
  float* rowsum = Emb + (size_t)NN * DEMB;      // [NN]        (zeroed)
  float* H1     = rowsum + NN;                  // [NN][DMID]
  float* E1     = H1 + (size_t)NN * DMID;       // [NN][DEMB]
  float* sqv    = E1 + (size_t)NN * DEMB;       // [NN]
  float* invv   = sqv + NN;                     // [NN]

  size_t zbytes = ((size_t)NN * DMID + (size_t)NN * DEMB + NN) * sizeof(float);
  hipMemsetAsync(d_ws, 0, zbytes, stream);

  // 1) H1 = X @ W1
  sgemm_kernel<128, 64, 16, 8, 4, false>
      <<<dim3(DMID / 64, NN / 128), 256, 0, stream>>>(X, W1, H1, NN, DMID, DIN);
  // 2) H1s = spmm(H1)
  spmm_kernel<DMID><<<NEDGE / (256 / (DMID / 4)), 256, 0, stream>>>(H1, ev, esrc, edst, H1s);
  // 3) E1 = relu(H1s) @ W2
  sgemm_kernel<64, 64, 16, 4, 4, true>
      <<<dim3(DEMB / 64, NN / 64), 256, 0, stream>>>(H1s, W2, E1, NN, DEMB, DMID);
  // 4) Emb = spmm(E1)
  spmm_kernel<DEMB><<<NEDGE / (256 / (DEMB / 4)), 256, 0, stream>>>(E1, ev, esrc, edst, Emb);
  // 5) sq = rowsum(Emb^2)
  sq_kernel<<<NN / 256, 256, 0, stream>>>(Emb, sqv);
  // 6) out = exp(-dist), rowsum accumulated
  dist_exp_kernel<<<dim3(NN / 128, NN / 128), 256, 0, stream>>>(Emb, sqv, out, rowsum);
  // 7) normalize + 1e-10
  inv_kernel<<<NN / 256, 256, 0, stream>>>(rowsum, invv);
  scale_kernel<<<(NN / 4) * (NN / 256), 256, 0, stream>>>(out, invv);
}

// Round 2
// 611.917 us; speedup vs baseline: 1.3840x; 1.3840x over previous
//
#include <hip/hip_runtime.h>
#include <cstddef>

constexpr int NN    = 8192;
constexpr int DIN   = 1024;
constexpr int DMID  = 256;
constexpr int DEMB  = 64;
constexpr int NEDGE = 65536;

// ---------------- generic fp32 tiled GEMM (all dims divide tile sizes) ----------------
template<int BM, int BN, int BK, int TM, int TN, bool RELUA>
__global__ __launch_bounds__(256) void sgemm_kernel(
    const float* __restrict__ A, const float* __restrict__ B,
    float* __restrict__ C, int M, int N, int K)
{
  constexpr int TX = BN / TN;
  constexpr int TY = BM / TM;
  static_assert(TX * TY == 256, "block must be 256 threads");
  __shared__ float As[BK][BM + 4];   // transposed: As[k][m]
  __shared__ float Bs[BK][BN + 4];   // Bs[k][n]

  const int tid = threadIdx.x;
  const int tx  = tid % TX;
  const int ty  = tid / TX;
  const int m0  = blockIdx.y * BM;
  const int n0  = blockIdx.x * BN;

  float acc[TM][TN];
#pragma unroll
  for (int i = 0; i < TM; ++i)
#pragma unroll
    for (int j = 0; j < TN; ++j) acc[i][j] = 0.f;

  constexpr int A_PER = (BM * BK / 4) / 256;
  constexpr int B_PER = (BK * BN / 4) / 256;
  static_assert((BM * BK / 4) % 256 == 0 && (BK * BN / 4) % 256 == 0, "tile load");

  for (int k0 = 0; k0 < K; k0 += BK) {
#pragma unroll
    for (int f = 0; f < A_PER; ++f) {
      int idx = tid + f * 256;            // float4 index in A tile
      int row = idx / (BK / 4);
      int kc  = (idx % (BK / 4)) * 4;
      float4 v = *(const float4*)(A + (size_t)(m0 + row) * K + k0 + kc);
      if (RELUA) {
        v.x = fmaxf(v.x, 0.f); v.y = fmaxf(v.y, 0.f);
        v.z = fmaxf(v.z, 0.f); v.w = fmaxf(v.w, 0.f);
      }
      As[kc + 0][row] = v.x; As[kc + 1][row] = v.y;
      As[kc + 2][row] = v.z; As[kc + 3][row] = v.w;
    }
#pragma unroll
    for (int f = 0; f < B_PER; ++f) {
      int idx = tid + f * 256;
      int kr  = idx / (BN / 4);
      int nc  = (idx % (BN / 4)) * 4;
      *(float4*)&Bs[kr][nc] = *(const float4*)(B + (size_t)(k0 + kr) * N + n0 + nc);
    }
    __syncthreads();
#pragma unroll
    for (int k = 0; k < BK; ++k) {
      float a[TM], b[TN];
#pragma unroll
      for (int i = 0; i < TM; i += 4)
        *(float4*)&a[i] = *(const float4*)&As[k][ty * TM + i];
#pragma unroll
      for (int j = 0; j < TN; j += 4)
        *(float4*)&b[j] = *(const float4*)&Bs[k][tx * TN + j];
#pragma unroll
      for (int i = 0; i < TM; ++i)
#pragma unroll
        for (int j = 0; j < TN; ++j)
          acc[i][j] = fmaf(a[i], b[j], acc[i][j]);
    }
    __syncthreads();
  }
#pragma unroll
  for (int i = 0; i < TM; ++i)
#pragma unroll
    for (int j = 0; j < TN; j += 4) {
      float4 v;
      v.x = acc[i][j]; v.y = acc[i][j + 1]; v.z = acc[i][j + 2]; v.w = acc[i][j + 3];
      *(float4*)(C + (size_t)(m0 + ty * TM + i) * N + n0 + tx * TN + j) = v;
    }
}

// ---------------- CSR build: histogram -> exclusive scan -> scatter ----------------
__global__ __launch_bounds__(256) void hist_kernel(const int* __restrict__ dst,
                                                   int* __restrict__ counts)
{
  int e = blockIdx.x * 256 + threadIdx.x;
  atomicAdd(&counts[dst[e]], 1);
}

// exclusive scan of NN ints, single block of 256 threads (32 elems/thread)
__global__ __launch_bounds__(256) void scan_kernel(const int* __restrict__ counts,
                                                   int* __restrict__ row_start)
{
  __shared__ int sums[256];
  const int t = threadIdx.x;
  int local[32];
  int s = 0;
#pragma unroll
  for (int i = 0; i < 32; ++i) { local[i] = counts[t * 32 + i]; s += local[i]; }
  sums[t] = s;
  __syncthreads();
  for (int off = 1; off < 256; off <<= 1) {
    int v = (t >= off) ? sums[t - off] : 0;
    __syncthreads();
    sums[t] += v;
    __syncthreads();
  }
  int base = (t == 0) ? 0 : sums[t - 1];
#pragma unroll
  for (int i = 0; i < 32; ++i) { row_start[t * 32 + i] = base; base += local[i]; }
  if (t == 255) row_start[NN] = base;
}

__global__ __launch_bounds__(256) void scatter_kernel(
    const int* __restrict__ src, const float* __restrict__ val,
    const int* __restrict__ dst, const int* __restrict__ row_start,
    int* __restrict__ cursor, int* __restrict__ csr_src, float* __restrict__ csr_val)
{
  int e = blockIdx.x * 256 + threadIdx.x;
  int d = dst[e];
  int pos = row_start[d] + atomicAdd(&cursor[d], 1);
  csr_src[pos] = src[e];
  csr_val[pos] = val[e];
}

// ---------------- CSR spmm: one wave per output row, no atomics ----------------
// D=256: lane owns 4 cols (float4). D=64: lane owns 1 col; optional fused sq-norm.
template<int D, bool SQ>
__global__ __launch_bounds__(256) void spmm_csr_kernel(
    const float* __restrict__ H, const int* __restrict__ row_start,
    const int* __restrict__ csr_src, const float* __restrict__ csr_val,
    float* __restrict__ out, float* __restrict__ sqv)
{
  const int lane = threadIdx.x & 63;
  const int wave = threadIdx.x >> 6;
  const int r = blockIdx.x * 4 + wave;
  const int e0 = row_start[r];
  const int e1 = row_start[r + 1];

  if (D == 256) {
    float4 acc = make_float4(0.f, 0.f, 0.f, 0.f);
    const int c = lane * 4;
    for (int e = e0; e < e1; ++e) {
      const int s   = csr_src[e];
      const float v = csr_val[e];
      float4 h = *(const float4*)(H + (size_t)s * 256 + c);
      acc.x = fmaf(v, h.x, acc.x);
      acc.y = fmaf(v, h.y, acc.y);
      acc.z = fmaf(v, h.z, acc.z);
      acc.w = fmaf(v, h.w, acc.w);
    }
    *(float4*)(out + (size_t)r * 256 + c) = acc;
  } else {
    float acc = 0.f;
    for (int e = e0; e < e1; ++e) {
      const int s   = csr_src[e];
      const float v = csr_val[e];
      acc = fmaf(v, H[(size_t)s * 64 + lane], acc);
    }
    out[(size_t)r * 64 + lane] = acc;
    if (SQ) {
      float sq = acc * acc;
#pragma unroll
      for (int off = 32; off; off >>= 1) sq += __shfl_xor(sq, off, 64);
      if (lane == 0) sqv[r] = sq;
    }
  }
}

// ---------------- dist = sq_i + sq_j - 2*Emb@Emb.T ; write exp(-dist), accumulate rowsums ----
__global__ __launch_bounds__(256) void dist_exp_kernel(
    const float* __restrict__ E, const float* __restrict__ sq,
    float* __restrict__ out, float* __restrict__ rowsum)
{
  __shared__ float As[16][132];
  __shared__ float Bs[16][132];
  __shared__ float red[128][17];
  const int tid = threadIdx.x;
  const int tx  = tid % 16;
  const int ty  = tid / 16;
  const int i0  = blockIdx.y * 128;
  const int j0  = blockIdx.x * 128;

  float acc[8][8];
#pragma unroll
  for (int i = 0; i < 8; ++i)
#pragma unroll
    for (int j = 0; j < 8; ++j) acc[i][j] = 0.f;

  for (int k0 = 0; k0 < DEMB; k0 += 16) {
#pragma unroll
    for (int f = 0; f < 2; ++f) {
      int idx = tid + f * 256;
      int row = idx / 4;
      int kc  = (idx % 4) * 4;
      float4 a = *(const float4*)(E + (size_t)(i0 + row) * DEMB + k0 + kc);
      As[kc + 0][row] = a.x; As[kc + 1][row] = a.y; As[kc + 2][row] = a.z; As[kc + 3][row] = a.w;
      float4 b = *(const float4*)(E + (size_t)(j0 + row) * DEMB + k0 + kc);
      Bs[kc + 0][row] = b.x; Bs[kc + 1][row] = b.y; Bs[kc + 2][row] = b.z; Bs[kc + 3][row] = b.w;
    }
    __syncthreads();
#pragma unroll
    for (int k = 0; k < 16; ++k) {
      float a[8], b[8];
      *(float4*)&a[0] = *(const float4*)&As[k][ty * 8];
      *(float4*)&a[4] = *(const float4*)&As[k][ty * 8 + 4];
      *(float4*)&b[0] = *(const float4*)&Bs[k][tx * 8];
      *(float4*)&b[4] = *(const float4*)&Bs[k][tx * 8 + 4];
#pragma unroll
      for (int i = 0; i < 8; ++i)
#pragma unroll
        for (int j = 0; j < 8; ++j)
          acc[i][j] = fmaf(a[i], b[j], acc[i][j]);
    }
    __syncthreads();
  }

  float si[8], sj[8];
#pragma unroll
  for (int i = 0; i < 8; ++i) si[i] = sq[i0 + ty * 8 + i];
#pragma unroll
  for (int j = 0; j < 8; ++j) sj[j] = sq[j0 + tx * 8 + j];

#pragma unroll
  for (int i = 0; i < 8; ++i) {
    float evv[8];
    float rp = 0.f;
#pragma unroll
    for (int j = 0; j < 8; ++j) {
      // -dist = 2*dot - sq_i - sq_j ; dist_ii == 0 so no overflow, max-subtract unneeded
      evv[j] = __expf(fmaf(2.f, acc[i][j], -si[i] - sj[j]));
      rp += evv[j];
    }
    float4 e0, e1;
    e0.x = evv[0]; e0.y = evv[1]; e0.z = evv[2]; e0.w = evv[3];
    e1.x = evv[4]; e1.y = evv[5]; e1.z = evv[6]; e1.w = evv[7];
    size_t base = (size_t)(i0 + ty * 8 + i) * NN + j0 + tx * 8;
    *(float4*)(out + base)     = e0;
    *(float4*)(out + base + 4) = e1;
    red[ty * 8 + i][tx] = rp;
  }
  __syncthreads();
  if (tid < 128) {
    float s = 0.f;
#pragma unroll
    for (int t = 0; t < 16; ++t) s += red[tid][t];
    atomicAdd(rowsum + i0 + tid, s);
  }
}

// ---------------- normalize: out = out / rowsum[row] + 1e-10 ----------------
__global__ __launch_bounds__(256) void scale_kernel(float* __restrict__ out,
                                                    const float* __restrict__ rowsum)
{
  size_t idx = (size_t)blockIdx.x * 256 + threadIdx.x;  // float4 index
  int row = (int)(idx >> 11);                           // 2048 float4 per row
  float s = 1.f / rowsum[row];
  float4* p = (float4*)out + idx;
  float4 v = *p;
  v.x = fmaf(v.x, s, 1e-10f);
  v.y = fmaf(v.y, s, 1e-10f);
  v.z = fmaf(v.z, s, 1e-10f);
  v.w = fmaf(v.w, s, 1e-10f);
  *p = v;
}

extern "C" void kernel_launch(void* const* d_in, const int* in_sizes, int n_in,
                              void* d_out, int out_size, void* d_ws, size_t ws_size,
                              hipStream_t stream)
{
  const float* X  = (const float*)d_in[0];
  const float* W1 = (const float*)d_in[1];
  const float* W2 = (const float*)d_in[2];
  const float* ev = (const float*)d_in[3];
  const int* esrc = (const int*)d_in[4];
  const int* edst = (const int*)d_in[5];
  float* out = (float*)d_out;

  // workspace layout:
  // [zero block: counts | cursor | rowsum]  [row_start | csr_src | csr_val | H1 | H1s | E1 | Emb | sq]
  int*   counts   = (int*)d_ws;                       // [NN]   (zeroed)
  int*   cursor   = counts + NN;                      // [NN]   (zeroed)
  float* rowsum   = (float*)(cursor + NN);            // [NN]   (zeroed)
  int*   row_start= (int*)(rowsum + NN);              // [NN+1]
  int*   csr_src  = row_start + NN + 1;               // [NEDGE]
  float* csr_val  = (float*)(csr_src + NEDGE);        // [NEDGE]
  float* H1       = csr_val + NEDGE;                  // [NN][DMID]
  float* H1s      = H1 + (size_t)NN * DMID;           // [NN][DMID]
  float* E1       = H1s + (size_t)NN * DMID;          // [NN][DEMB]
  float* Emb      = E1 + (size_t)NN * DEMB;           // [NN][DEMB]
  float* sqv      = Emb + (size_t)NN * DEMB;          // [NN]

  hipMemsetAsync(d_ws, 0, (size_t)3 * NN * 4, stream);

  // CSR build (int atomics only, ~65k ops)
  hist_kernel<<<NEDGE / 256, 256, 0, stream>>>(edst, counts);
  scan_kernel<<<1, 256, 0, stream>>>(counts, row_start);
  scatter_kernel<<<NEDGE / 256, 256, 0, stream>>>(esrc, ev, edst, row_start, cursor,
                                                  csr_src, csr_val);

  // 1) H1 = X @ W1
  sgemm_kernel<128, 64, 16, 8, 4, false>
      <<<dim3(DMID / 64, NN / 128), 256, 0, stream>>>(X, W1, H1, NN, DMID, DIN);
  // 2) H1s = spmm(H1)   — gather CSR, no atomics
  spmm_csr_kernel<DMID, false><<<NN / 4, 256, 0, stream>>>(H1, row_start, csr_src, csr_val,
                                                           H1s, nullptr);
  // 3) E1 = relu(H1s) @ W2
  sgemm_kernel<64, 64, 16, 4, 4, true>
      <<<dim3(DEMB / 64, NN / 64), 256, 0, stream>>>(H1s, W2, E1, NN, DEMB, DMID);
  // 4) Emb = spmm(E1) ; fused sq = rowsum(Emb^2)
  spmm_csr_kernel<DEMB, true><<<NN / 4, 256, 0, stream>>>(E1, row_start, csr_src, csr_val,
                                                          Emb, sqv);
  // 5) out = exp(-dist), rowsum accumulated
  dist_exp_kernel<<<dim3(NN / 128, NN / 128), 256, 0, stream>>>(Emb, sqv, out, rowsum);
  // 6) normalize + 1e-10
  scale_kernel<<<(NN / 4) * (NN / 256), 256, 0, stream>>>(out, rowsum);
}

// Round 3
// 500.760 us; speedup vs baseline: 1.6912x; 1.2220x over previous
//
#include <hip/hip_runtime.h>
#include <cstddef>

constexpr int NN    = 8192;
constexpr int DIN   = 1024;
constexpr int DMID  = 256;
constexpr int DEMB  = 64;
constexpr int NEDGE = 65536;

typedef __attribute__((ext_vector_type(8))) short bf16x8;
typedef __attribute__((ext_vector_type(4))) float f32x4;
#define MFMA16(a, b, c) __builtin_amdgcn_mfma_f32_16x16x32_bf16((a), (b), (c), 0, 0, 0)

// ---------------- bf16 hi/lo split helpers ----------------
__device__ __forceinline__ unsigned short bf16_rne(float x) {
  unsigned u = __float_as_uint(x);
  return (unsigned short)((u + 0x7FFFu + ((u >> 16) & 1u)) >> 16);
}
__device__ __forceinline__ void bf16_split(float x, unsigned short& h, unsigned short& l) {
  unsigned short hb = bf16_rne(x);
  float hf = __uint_as_float((unsigned)hb << 16);
  h = hb;
  l = bf16_rne(x - hf);
}

// ---------------- conversions ----------------
__global__ __launch_bounds__(256) void split_kernel(const float* __restrict__ src,
                                                    unsigned short* __restrict__ hi,
                                                    unsigned short* __restrict__ lo)
{
  size_t idx = ((size_t)blockIdx.x * 256 + threadIdx.x) * 4;
  float4 v = *(const float4*)(src + idx);
  ushort4 h, l;
  bf16_split(v.x, h.x, l.x);
  bf16_split(v.y, h.y, l.y);
  bf16_split(v.z, h.z, l.z);
  bf16_split(v.w, h.w, l.w);
  *(ushort4*)(hi + idx) = h;
  *(ushort4*)(lo + idx) = l;
}

// W1 [1024][256] -> W1T hi/lo [256][1024]
__global__ __launch_bounds__(256) void w1t_kernel(const float* __restrict__ W1,
                                                  unsigned short* __restrict__ h,
                                                  unsigned short* __restrict__ l)
{
  int idx = blockIdx.x * 256 + threadIdx.x;   // over [256][1024]
  int n = idx >> 10, k = idx & 1023;
  bf16_split(W1[k * 256 + n], h[idx], l[idx]);
}

// W2 [256][64] -> W2T hi/lo [64][256]
__global__ __launch_bounds__(256) void w2t_kernel(const float* __restrict__ W2,
                                                  unsigned short* __restrict__ h,
                                                  unsigned short* __restrict__ l)
{
  int idx = blockIdx.x * 256 + threadIdx.x;   // over [64][256]
  int n = idx >> 8, k = idx & 255;
  bf16_split(W2[k * 64 + n], h[idx], l[idx]);
}

// ---------------- CSR build ----------------
__global__ __launch_bounds__(256) void hist_kernel(const int* __restrict__ dst,
                                                   int* __restrict__ counts)
{
  int e = blockIdx.x * 256 + threadIdx.x;
  atomicAdd(&counts[dst[e]], 1);
}

__global__ __launch_bounds__(256) void scan_kernel(const int* __restrict__ counts,
                                                   int* __restrict__ row_start)
{
  __shared__ int sums[256];
  const int t = threadIdx.x;
  int local[32];
  int s = 0;
#pragma unroll
  for (int i = 0; i < 32; ++i) { local[i] = counts[t * 32 + i]; s += local[i]; }
  sums[t] = s;
  __syncthreads();
  for (int off = 1; off < 256; off <<= 1) {
    int v = (t >= off) ? sums[t - off] : 0;
    __syncthreads();
    sums[t] += v;
    __syncthreads();
  }
  int base = (t == 0) ? 0 : sums[t - 1];
#pragma unroll
  for (int i = 0; i < 32; ++i) { row_start[t * 32 + i] = base; base += local[i]; }
  if (t == 255) row_start[NN] = base;
}

__global__ __launch_bounds__(256) void scatter_kernel(
    const int* __restrict__ src, const float* __restrict__ val,
    const int* __restrict__ dst, const int* __restrict__ row_start,
    int* __restrict__ cursor, int* __restrict__ csr_src, float* __restrict__ csr_val)
{
  int e = blockIdx.x * 256 + threadIdx.x;
  int d = dst[e];
  int pos = row_start[d] + atomicAdd(&cursor[d], 1);
  csr_src[pos] = src[e];
  csr_val[pos] = val[e];
}

// ---------------- GEMM1: H1 = X @ W1 via bf16-split MFMA ----------------
// Xh/Xl [8192][1024], Wh/Wl = W1T [256][1024]; C fp32 [8192][256]
__global__ __launch_bounds__(256) void gemm1_kernel(
    const unsigned short* __restrict__ Xh, const unsigned short* __restrict__ Xl,
    const unsigned short* __restrict__ Wh, const unsigned short* __restrict__ Wl,
    float* __restrict__ C)
{
  const int lane = threadIdx.x & 63;
  const int wave = threadIdx.x >> 6;
  const int m0 = blockIdx.y * 64 + wave * 16;
  const int n0 = blockIdx.x * 64;
  const int rl = lane & 15;
  const int kq = (lane >> 4) * 8;
  f32x4 zero = {0.f, 0.f, 0.f, 0.f};
  f32x4 acc[4] = {zero, zero, zero, zero};
  for (int s = 0; s < DIN / 32; ++s) {
    const int kb = s * 32 + kq;
    bf16x8 ah = *(const bf16x8*)(Xh + (size_t)(m0 + rl) * DIN + kb);
    bf16x8 al = *(const bf16x8*)(Xl + (size_t)(m0 + rl) * DIN + kb);
#pragma unroll
    for (int ns = 0; ns < 4; ++ns) {
      const size_t rb = (size_t)(n0 + ns * 16 + rl) * DIN + kb;
      bf16x8 bh = *(const bf16x8*)(Wh + rb);
      bf16x8 bl = *(const bf16x8*)(Wl + rb);
      acc[ns] = MFMA16(ah, bh, acc[ns]);
      acc[ns] = MFMA16(ah, bl, acc[ns]);
      acc[ns] = MFMA16(al, bh, acc[ns]);
    }
  }
  const int rq = (lane >> 4) * 4;
#pragma unroll
  for (int ns = 0; ns < 4; ++ns)
#pragma unroll
    for (int r = 0; r < 4; ++r)
      C[(size_t)(m0 + rq + r) * DMID + n0 + ns * 16 + rl] = acc[ns][r];
}

// ---------------- GEMM2: E1 = relu(H1s) @ W2 via bf16-split MFMA ----------------
// Ah/Al [8192][256] (already relu'd+split), Wh/Wl = W2T [64][256]; C fp32 [8192][64]
__global__ __launch_bounds__(64) void gemm2_kernel(
    const unsigned short* __restrict__ Ah, const unsigned short* __restrict__ Al,
    const unsigned short* __restrict__ Wh, const unsigned short* __restrict__ Wl,
    float* __restrict__ C)
{
  const int lane = threadIdx.x;
  const int m0 = blockIdx.x * 16;
  const int rl = lane & 15;
  const int kq = (lane >> 4) * 8;
  f32x4 zero = {0.f, 0.f, 0.f, 0.f};
  f32x4 acc[4] = {zero, zero, zero, zero};
  for (int s = 0; s < DMID / 32; ++s) {
    const int kb = s * 32 + kq;
    bf16x8 ah = *(const bf16x8*)(Ah + (size_t)(m0 + rl) * DMID + kb);
    bf16x8 al = *(const bf16x8*)(Al + (size_t)(m0 + rl) * DMID + kb);
#pragma unroll
    for (int ns = 0; ns < 4; ++ns) {
      const size_t rb = (size_t)(ns * 16 + rl) * DMID + kb;
      bf16x8 bh = *(const bf16x8*)(Wh + rb);
      bf16x8 bl = *(const bf16x8*)(Wl + rb);
      acc[ns] = MFMA16(ah, bh, acc[ns]);
      acc[ns] = MFMA16(ah, bl, acc[ns]);
      acc[ns] = MFMA16(al, bh, acc[ns]);
    }
  }
  const int rq = (lane >> 4) * 4;
#pragma unroll
  for (int ns = 0; ns < 4; ++ns)
#pragma unroll
    for (int r = 0; r < 4; ++r)
      C[(size_t)(m0 + rq + r) * DEMB + ns * 16 + rl] = acc[ns][r];
}

// ---------------- spmm1: H1s = relu-free gather; emits relu+bf16-split ----------------
__global__ __launch_bounds__(256) void spmm1_kernel(
    const float* __restrict__ H, const int* __restrict__ row_start,
    const int* __restrict__ csr_src, const float* __restrict__ csr_val,
    unsigned short* __restrict__ outh, unsigned short* __restrict__ outl)
{
  const int lane = threadIdx.x & 63;
  const int wave = threadIdx.x >> 6;
  const int r = blockIdx.x * 4 + wave;
  const int e0 = row_start[r];
  const int e1 = row_start[r + 1];
  const int c = lane * 4;
  float4 acc = make_float4(0.f, 0.f, 0.f, 0.f);
  for (int e = e0; e < e1; ++e) {
    const int s   = csr_src[e];
    const float v = csr_val[e];
    float4 h = *(const float4*)(H + (size_t)s * DMID + c);
    acc.x = fmaf(v, h.x, acc.x);
    acc.y = fmaf(v, h.y, acc.y);
    acc.z = fmaf(v, h.z, acc.z);
    acc.w = fmaf(v, h.w, acc.w);
  }
  acc.x = fmaxf(acc.x, 0.f); acc.y = fmaxf(acc.y, 0.f);
  acc.z = fmaxf(acc.z, 0.f); acc.w = fmaxf(acc.w, 0.f);
  ushort4 h, l;
  bf16_split(acc.x, h.x, l.x);
  bf16_split(acc.y, h.y, l.y);
  bf16_split(acc.z, h.z, l.z);
  bf16_split(acc.w, h.w, l.w);
  *(ushort4*)(outh + (size_t)r * DMID + c) = h;
  *(ushort4*)(outl + (size_t)r * DMID + c) = l;
}

// ---------------- spmm2: Emb = spmm(E1); emits bf16-split + row sq-norm ----------------
__global__ __launch_bounds__(256) void spmm2_kernel(
    const float* __restrict__ H, const int* __restrict__ row_start,
    const int* __restrict__ csr_src, const float* __restrict__ csr_val,
    unsigned short* __restrict__ EmbH, unsigned short* __restrict__ EmbL,
    float* __restrict__ sqv)
{
  const int lane = threadIdx.x & 63;
  const int wave = threadIdx.x >> 6;
  const int r = blockIdx.x * 4 + wave;
  const int e0 = row_start[r];
  const int e1 = row_start[r + 1];
  float acc = 0.f;
  for (int e = e0; e < e1; ++e)
    acc = fmaf(csr_val[e], H[(size_t)csr_src[e] * DEMB + lane], acc);
  unsigned short h, l;
  bf16_split(acc, h, l);
  EmbH[(size_t)r * DEMB + lane] = h;
  EmbL[(size_t)r * DEMB + lane] = l;
  float sq = acc * acc;
#pragma unroll
  for (int off = 32; off; off >>= 1) sq += __shfl_xor(sq, off, 64);
  if (lane == 0) sqv[r] = sq;
}

// ---------------- shared MFMA core: 64x64 dot-products per wave (K=64, 3-split) ----------
__device__ __forceinline__ void dist_tile_accum(
    const unsigned short* __restrict__ EH, const unsigned short* __restrict__ EL,
    int ibase, int jbase, int lane, f32x4 (&acc)[4][4])
{
  const int rl = lane & 15;
  const int kq = (lane >> 4) * 8;
#pragma unroll
  for (int s = 0; s < 2; ++s) {
    const int kb = s * 32 + kq;
    bf16x8 ah[4], al[4], bh[4], bl[4];
#pragma unroll
    for (int t = 0; t < 4; ++t) {
      const size_t ra = (size_t)(ibase + t * 16 + rl) * DEMB + kb;
      ah[t] = *(const bf16x8*)(EH + ra);
      al[t] = *(const bf16x8*)(EL + ra);
      const size_t rb = (size_t)(jbase + t * 16 + rl) * DEMB + kb;
      bh[t] = *(const bf16x8*)(EH + rb);
      bl[t] = *(const bf16x8*)(EL + rb);
    }
#pragma unroll
    for (int ms = 0; ms < 4; ++ms)
#pragma unroll
      for (int ns = 0; ns < 4; ++ns) {
        acc[ms][ns] = MFMA16(ah[ms], bh[ns], acc[ms][ns]);
        acc[ms][ns] = MFMA16(ah[ms], bl[ns], acc[ms][ns]);
        acc[ms][ns] = MFMA16(al[ms], bh[ns], acc[ms][ns]);
      }
  }
}

// ---------------- pass1: softmax row sums (no NxN write) ----------------
__global__ __launch_bounds__(256) void rowsum_kernel(
    const unsigned short* __restrict__ EH, const unsigned short* __restrict__ EL,
    const float* __restrict__ sq, float* __restrict__ rowsum)
{
  const int lane = threadIdx.x & 63;
  const int wave = threadIdx.x >> 6;
  const int wr = wave >> 1, wc = wave & 1;
  const int ibase = blockIdx.x * 128 + wr * 64;
  const int jslab = blockIdx.y * 1024;
  const int rl = lane & 15;
  const int rq = (lane >> 4) * 4;

  float si[4][4];
#pragma unroll
  for (int ms = 0; ms < 4; ++ms)
#pragma unroll
    for (int r = 0; r < 4; ++r) si[ms][r] = sq[ibase + ms * 16 + rq + r];

  float rs[4][4] = {};
  f32x4 zero = {0.f, 0.f, 0.f, 0.f};
  for (int jt = 0; jt < 8; ++jt) {
    const int jbase = jslab + jt * 128 + wc * 64;
    f32x4 acc[4][4];
#pragma unroll
    for (int ms = 0; ms < 4; ++ms)
#pragma unroll
      for (int ns = 0; ns < 4; ++ns) acc[ms][ns] = zero;
    dist_tile_accum(EH, EL, ibase, jbase, lane, acc);
    float sj[4];
#pragma unroll
    for (int ns = 0; ns < 4; ++ns) sj[ns] = sq[jbase + ns * 16 + rl];
#pragma unroll
    for (int ms = 0; ms < 4; ++ms)
#pragma unroll
      for (int ns = 0; ns < 4; ++ns)
#pragma unroll
        for (int r = 0; r < 4; ++r)
          rs[ms][r] += __expf(fmaf(2.f, acc[ms][ns][r], -si[ms][r] - sj[ns]));
  }
#pragma unroll
  for (int ms = 0; ms < 4; ++ms)
#pragma unroll
    for (int r = 0; r < 4; ++r) {
      float v = rs[ms][r];
      v += __shfl_xor(v, 1, 64);
      v += __shfl_xor(v, 2, 64);
      v += __shfl_xor(v, 4, 64);
      v += __shfl_xor(v, 8, 64);
      if (rl == 0) atomicAdd(&rowsum[ibase + ms * 16 + rq + r], v);
    }
}

__global__ __launch_bounds__(256) void inv_kernel(const float* __restrict__ rowsum,
                                                  float* __restrict__ rinv)
{
  int i = blockIdx.x * 256 + threadIdx.x;
  rinv[i] = 1.f / rowsum[i];
}

// ---------------- pass2: recompute dist, write normalized softmax + 1e-10 ----------------
__global__ __launch_bounds__(256) void dist_write_kernel(
    const unsigned short* __restrict__ EH, const unsigned short* __restrict__ EL,
    const float* __restrict__ sq, const float* __restrict__ rinv,
    float* __restrict__ out)
{
  const int lane = threadIdx.x & 63;
  const int wave = threadIdx.x >> 6;
  const int wr = wave >> 1, wc = wave & 1;
  const int ibase = blockIdx.y * 128 + wr * 64;
  const int jbase = blockIdx.x * 128 + wc * 64;
  const int rl = lane & 15;
  const int rq = (lane >> 4) * 4;

  f32x4 zero = {0.f, 0.f, 0.f, 0.f};
  f32x4 acc[4][4];
#pragma unroll
  for (int ms = 0; ms < 4; ++ms)
#pragma unroll
    for (int ns = 0; ns < 4; ++ns) acc[ms][ns] = zero;
  dist_tile_accum(EH, EL, ibase, jbase, lane, acc);

  float si[4][4], ri[4][4], sj[4];
#pragma unroll
  for (int ms = 0; ms < 4; ++ms)
#pragma unroll
    for (int r = 0; r < 4; ++r) {
      const int i = ibase + ms * 16 + rq + r;
      si[ms][r] = sq[i];
      ri[ms][r] = rinv[i];
    }
#pragma unroll
  for (int ns = 0; ns < 4; ++ns) sj[ns] = sq[jbase + ns * 16 + rl];

#pragma unroll
  for (int ms = 0; ms < 4; ++ms)
#pragma unroll
    for (int r = 0; r < 4; ++r) {
      const size_t row = (size_t)(ibase + ms * 16 + rq + r) * NN;
#pragma unroll
      for (int ns = 0; ns < 4; ++ns) {
        float v = __expf(fmaf(2.f, acc[ms][ns][r], -si[ms][r] - sj[ns]));
        out[row + jbase + ns * 16 + rl] = fmaf(v, ri[ms][r], 1e-10f);
      }
    }
}

// ---------------- launch ----------------
extern "C" void kernel_launch(void* const* d_in, const int* in_sizes, int n_in,
                              void* d_out, int out_size, void* d_ws, size_t ws_size,
                              hipStream_t stream)
{
  const float* X  = (const float*)d_in[0];
  const float* W1 = (const float*)d_in[1];
  const float* W2 = (const float*)d_in[2];
  const float* ev = (const float*)d_in[3];
  const int* esrc = (const int*)d_in[4];
  const int* edst = (const int*)d_in[5];
  float* out = (float*)d_out;

  char* p = (char*)d_ws;
  auto alloc = [&](size_t bytes) { char* q = p; p += (bytes + 255) & ~(size_t)255; return q; };

  // zero block first (single memset): counts, cursor, rowsum
  int*   counts    = (int*)alloc(NN * 4);
  int*   cursor    = (int*)alloc(NN * 4);
  float* rowsum    = (float*)alloc(NN * 4);
  int*   row_start = (int*)alloc((NN + 1) * 4);
  int*   csr_src   = (int*)alloc(NEDGE * 4);
  float* csr_val   = (float*)alloc(NEDGE * 4);
  float* sqv       = (float*)alloc(NN * 4);
  float* rinv      = (float*)alloc(NN * 4);
  float* H1        = (float*)alloc((size_t)NN * DMID * 4);
  float* E1        = (float*)alloc((size_t)NN * DEMB * 4);
  unsigned short* Xh   = (unsigned short*)alloc((size_t)NN * DIN * 2);
  unsigned short* Xl   = (unsigned short*)alloc((size_t)NN * DIN * 2);
  unsigned short* W1Th = (unsigned short*)alloc((size_t)DMID * DIN * 2);
  unsigned short* W1Tl = (unsigned short*)alloc((size_t)DMID * DIN * 2);
  unsigned short* W2Th = (unsigned short*)alloc((size_t)DEMB * DMID * 2);
  unsigned short* W2Tl = (unsigned short*)alloc((size_t)DEMB * DMID * 2);
  unsigned short* H1sh = (unsigned short*)alloc((size_t)NN * DMID * 2);
  unsigned short* H1sl = (unsigned short*)alloc((size_t)NN * DMID * 2);
  unsigned short* EmbH = (unsigned short*)alloc((size_t)NN * DEMB * 2);
  unsigned short* EmbL = (unsigned short*)alloc((size_t)NN * DEMB * 2);

  hipMemsetAsync(d_ws, 0, (size_t)3 * NN * 4, stream);

  // conversions
  split_kernel<<<(size_t)NN * DIN / 1024, 256, 0, stream>>>(X, Xh, Xl);
  w1t_kernel<<<DMID * DIN / 256, 256, 0, stream>>>(W1, W1Th, W1Tl);
  w2t_kernel<<<DEMB * DMID / 256, 256, 0, stream>>>(W2, W2Th, W2Tl);

  // CSR build
  hist_kernel<<<NEDGE / 256, 256, 0, stream>>>(edst, counts);
  scan_kernel<<<1, 256, 0, stream>>>(counts, row_start);
  scatter_kernel<<<NEDGE / 256, 256, 0, stream>>>(esrc, ev, edst, row_start, cursor,
                                                  csr_src, csr_val);

  // H1 = X @ W1
  gemm1_kernel<<<dim3(DMID / 64, NN / 64), 256, 0, stream>>>(Xh, Xl, W1Th, W1Tl, H1);
  // H1s = relu(spmm(H1)) -> bf16 split
  spmm1_kernel<<<NN / 4, 256, 0, stream>>>(H1, row_start, csr_src, csr_val, H1sh, H1sl);
  // E1 = H1s @ W2
  gemm2_kernel<<<NN / 16, 64, 0, stream>>>(H1sh, H1sl, W2Th, W2Tl, E1);
  // Emb = spmm(E1) -> bf16 split + sq norms
  spmm2_kernel<<<NN / 4, 256, 0, stream>>>(E1, row_start, csr_src, csr_val, EmbH, EmbL, sqv);

  // pass1: softmax row sums
  rowsum_kernel<<<dim3(NN / 128, 8), 256, 0, stream>>>(EmbH, EmbL, sqv, rowsum);
  inv_kernel<<<NN / 256, 256, 0, stream>>>(rowsum, rinv);
  // pass2: write normalized output
  dist_write_kernel<<<dim3(NN / 128, NN / 128), 256, 0, stream>>>(EmbH, EmbL, sqv, rinv, out);
}